// Round 5
// baseline (648.665 us; speedup 1.0000x reference)
//
#include <hip/hip_runtime.h>
#include <math.h>

#define T_STEPS 1024
#define B_SIZE  512
#define D_IN    225
#define WT_K    228
#define LOG2E   1.4426950408889634f

__device__ __forceinline__ float fexp2(float x) {
#if __has_builtin(__builtin_amdgcn_exp2f)
  return __builtin_amdgcn_exp2f(x);
#else
  return exp2f(x);
#endif
}
__device__ __forceinline__ float frcp(float x) {
#if __has_builtin(__builtin_amdgcn_rcpf)
  return __builtin_amdgcn_rcpf(x);
#else
  return 1.0f / x;
#endif
}
#define SIG(x) frcp(1.0f + fexp2((x) * (-LOG2E)))
#define TH(x)  fmaf(2.0f, frcp(1.0f + fexp2((x) * (-2.0f * LOG2E))), -1.0f)

#define GL16(gp, lp) __builtin_amdgcn_global_load_lds(                          \
    (const __attribute__((address_space(1))) void*)(gp),                        \
    (__attribute__((address_space(3))) void*)(lp), 16, 0, 0)
#define GL4(gp, lp)  __builtin_amdgcn_global_load_lds(                          \
    (const __attribute__((address_space(1))) void*)(gp),                        \
    (__attribute__((address_space(3))) void*)(lp), 4, 0, 0)

#define WAIT_VM0() do {                                                         \
    asm volatile("s_waitcnt vmcnt(0)" ::: "memory");                            \
    __builtin_amdgcn_sched_barrier(0);                                          \
  } while (0)

// -------- Kernel 0: wt2[g*228+k] = Wih[g*225+k] (pad 0); bias at 4560 -------
__global__ __launch_bounds__(256)
void prep_wt(const float* __restrict__ Wih, const float* __restrict__ bih,
             const float* __restrict__ bhh, float* __restrict__ wt2)
{
  int i = blockIdx.x * 256 + threadIdx.x;      // 0..4607
  int g = i / WT_K, kk = i - g * WT_K;
  float v = 0.f;
  if (g < 20 && kk < 225) v = Wih[g * 225 + kk];
  if (i >= 4560 && i < 4580) v = bih[i - 4560] + bhh[i - 4560];
  wt2[i] = v;
}

// -------- Kernel 1: xg' (permuted) = x @ Wih0^T + b --------------------------
// Persistent 256 blocks x 256 thr; 32 tiles of 64 rows per block.
// Double-buffered x-stage via global_load_lds: tile t+1 loads issued BEFORE
// computing tile t, so the __syncthreads vmcnt(0) drain has full compute cover.
// Output layout: xg'[row*20 + 4*u + q] (unit-major float4 for the LSTM kernel).
__global__ __launch_bounds__(256)
void xg_gemm(const float* __restrict__ x, const float* __restrict__ wtg,
             float* __restrict__ xg)
{
  __shared__ __align__(16) float xs[2][64 * D_IN];   // 2 x 57600 B
  __shared__ __align__(16) float wt[4608];           // 18432 B (tot 133632 B)
  const int tid  = threadIdx.x;
  const int lane = tid & 63;
  const int w    = __builtin_amdgcn_readfirstlane(tid >> 6);   // 0..3

  // stage W_T + bias once (18 x 256-dword chunks, round-robin over waves)
  for (int m = w; m < 18; m += 4)
    GL16(wtg + m * 256 + lane * 4, wt + m * 256);

#define STAGE_TILE(TI, BUF)                                                    \
  { const float* src_ = x + (size_t)(TI) * (64 * D_IN);                        \
    float* dst_ = xs[BUF];                                                     \
    _Pragma("unroll")                                                          \
    for (int m = 0; m < 14; ++m)                                               \
      GL16(src_ + (w * 14 + m) * 256 + lane * 4, dst_ + (w * 14 + m) * 256);   \
    if (w == 0) GL4(src_ + 14336 + lane, dst_ + 14336); }

  const int tile0 = blockIdx.x * 32;
  STAGE_TILE(tile0, 0)
  __syncthreads();                       // wt + tile0 ready

  const int h16 = w * 16;                // wt row offset for this wave's gates
  for (int t = 0; t < 32; ++t) {
    const int cur = t & 1;
    if (t < 31) STAGE_TILE(tile0 + t + 1, cur ^ 1)

    float acc[5];
#pragma unroll
    for (int j = 0; j < 5; ++j) acc[j] = wt[4560 + 5 * w + j];
    const float* xr = xs[cur] + lane * D_IN;   // bank (lane+k)%32: conflict-free
    const float* wr = wt + (5 * w) * WT_K;     // wave-uniform -> broadcast reads
#pragma unroll 8
    for (int kb = 0; kb < 224; kb += 4) {
      float x0 = xr[kb], x1 = xr[kb + 1], x2 = xr[kb + 2], x3 = xr[kb + 3];
#pragma unroll
      for (int j = 0; j < 5; ++j) {
        const float4 wv = *(const float4*)(wr + j * WT_K + kb);
        acc[j] = fmaf(x0, wv.x, acc[j]);
        acc[j] = fmaf(x1, wv.y, acc[j]);
        acc[j] = fmaf(x2, wv.z, acc[j]);
        acc[j] = fmaf(x3, wv.w, acc[j]);
      }
    }
    {
      float xl = xr[224];
#pragma unroll
      for (int j = 0; j < 5; ++j) acc[j] = fmaf(xl, wr[j * WT_K + 224], acc[j]);
    }
    // permuted store: gate (5w+j) -> slot 4*j + w
    float* op = xg + ((size_t)(tile0 + t) * 64 + lane) * 20 + w;
#pragma unroll
    for (int j = 0; j < 5; ++j) op[4 * j] = acc[j];

    __syncthreads();   // vmcnt(0): t+1 loads (issued before compute) + drain
  }
#undef STAGE_TILE
}

// -------- Kernel 2: 6-stage pipeline in one half-wave; VMEM-free ticks ------
// Lanes (per 32-lane half): stage = l32/5 (L0,L1,FC1,L2,L3,FC2), u = l32%5;
// lanes 30,31 idle. Exchange: 10 ds_bpermute per tick. xg staged in LDS by
// 64-tick chunks (global_load_lds, double buffer); outputs staged in an LDS
// ring flushed per chunk. Single wave per block -> no barriers at all.
__global__ __launch_bounds__(64)
void lstm_fused(const float* __restrict__ xg, float* __restrict__ out,
              const float* __restrict__ l1_Whh0,
              const float* __restrict__ l1_Wih1, const float* __restrict__ l1_Whh1,
              const float* __restrict__ l1_bih1, const float* __restrict__ l1_bhh1,
              const float* __restrict__ fc1_W,  const float* __restrict__ fc1_b,
              const float* __restrict__ l2_Wih0, const float* __restrict__ l2_Whh0,
              const float* __restrict__ l2_bih0, const float* __restrict__ l2_bhh0,
              const float* __restrict__ l2_Wih1, const float* __restrict__ l2_Whh1,
              const float* __restrict__ l2_bih1, const float* __restrict__ l2_bhh1,
              const float* __restrict__ fc2_W,  const float* __restrict__ fc2_b)
{
  __shared__ __align__(16) float xq[2][2][1280];   // [buf][elem][64t*20]
  __shared__ float outb[2][64][5];                 // [elem][t&63][u]
  const int lane  = threadIdx.x & 63;
  const int half  = lane >> 5;
  const int l32   = lane & 31;
  const int stage = (l32 < 30) ? (l32 / 5) : 6;
  const int u     = (l32 < 30) ? (l32 - stage * 5) : 0;
  const int b0    = blockIdx.x * 2;

  const bool is_l0   = (stage == 0);
  const bool is_relu = (stage == 2);
  const bool is_fc   = (stage == 2) || (stage == 5);
  const bool is_fc2  = (stage == 5);

  float wi[4][5] = {}, wh[4][5] = {}, bs[4] = {}, wf[5] = {};
  float fb = 0.f;
  if (stage == 0) {
#pragma unroll
    for (int q = 0; q < 4; ++q)
#pragma unroll
      for (int j = 0; j < 5; ++j) wh[q][j] = l1_Whh0[(u + 5 * q) * 5 + j];
  } else if (stage == 1) {
#pragma unroll
    for (int q = 0; q < 4; ++q) {
#pragma unroll
      for (int j = 0; j < 5; ++j) {
        wi[q][j] = l1_Wih1[(u + 5 * q) * 5 + j];
        wh[q][j] = l1_Whh1[(u + 5 * q) * 5 + j];
      }
      bs[q] = l1_bih1[u + 5 * q] + l1_bhh1[u + 5 * q];
    }
  } else if (stage == 3) {
#pragma unroll
    for (int q = 0; q < 4; ++q) {
#pragma unroll
      for (int j = 0; j < 5; ++j) {
        wi[q][j] = l2_Wih0[(u + 5 * q) * 5 + j];
        wh[q][j] = l2_Whh0[(u + 5 * q) * 5 + j];
      }
      bs[q] = l2_bih0[u + 5 * q] + l2_bhh0[u + 5 * q];
    }
  } else if (stage == 4) {
#pragma unroll
    for (int q = 0; q < 4; ++q) {
#pragma unroll
      for (int j = 0; j < 5; ++j) {
        wi[q][j] = l2_Wih1[(u + 5 * q) * 5 + j];
        wh[q][j] = l2_Whh1[(u + 5 * q) * 5 + j];
      }
      bs[q] = l2_bih1[u + 5 * q] + l2_bhh1[u + 5 * q];
    }
  } else if (stage == 2) {
#pragma unroll
    for (int j = 0; j < 5; ++j) wf[j] = fc1_W[u * 5 + j];
    fb = fc1_b[u];
  } else if (stage == 5) {
#pragma unroll
    for (int j = 0; j < 5; ++j) wf[j] = fc2_W[u * 5 + j];
    fb = fc2_b[u];
  }

  // bpermute byte-indices (loop-invariant). in <- prev stage's lanes, hh <- own.
  int ii[5], ih[5];
  const int bse = half * 32;
  const int inb = (stage >= 1 && stage <= 5) ? (stage - 1) * 5 : 0;
  const int hb_ = (stage <= 5) ? stage * 5 : 0;
#pragma unroll
  for (int j = 0; j < 5; ++j) {
    ii[j] = (bse + inb + j) * 4;
    ih[j] = (bse + hb_ + j) * 4;
  }

  const float* src0 = xg + (size_t)(b0 + 0) * T_STEPS * 20;
  const float* src1 = xg + (size_t)(b0 + 1) * T_STEPS * 20;

#define STAGE_CHUNK(CH, BUF)                                                   \
  { const float* s0_ = src0 + (CH) * 1280;                                     \
    const float* s1_ = src1 + (CH) * 1280;                                     \
    float* d0_ = &xq[BUF][0][0];                                               \
    float* d1_ = &xq[BUF][1][0];                                               \
    _Pragma("unroll")                                                          \
    for (int m = 0; m < 5; ++m) {                                              \
      GL16(s0_ + m * 256 + lane * 4, d0_ + m * 256);                           \
      GL16(s1_ + m * 256 + lane * 4, d1_ + m * 256);                           \
    } }

#define TICK(K)                                                                \
  { const int k_ = (K);                                                        \
    const int buf_  = (k_ >> 6) & 1;                                           \
    const int slot_ = k_ & 63;                                                 \
    const int hvi_ = __float_as_int(hv);                                       \
    float in[5], hh[5];                                                        \
    _Pragma("unroll")                                                          \
    for (int j = 0; j < 5; ++j) {                                              \
      in[j] = __int_as_float(__builtin_amdgcn_ds_bpermute(ii[j], hvi_));       \
      hh[j] = __int_as_float(__builtin_amdgcn_ds_bpermute(ih[j], hvi_));       \
    }                                                                          \
    const float4 Q = *(const float4*)&xq[buf_][half][slot_ * 20 + 4 * u];      \
    const float qv_[4] = {Q.x, Q.y, Q.z, Q.w};                                 \
    float pre[4];                                                              \
    _Pragma("unroll")                                                          \
    for (int q = 0; q < 4; ++q) {                                              \
      float p = is_l0 ? qv_[q] : bs[q];                                        \
      _Pragma("unroll")                                                        \
      for (int j = 0; j < 5; ++j) p = fmaf(wi[q][j], in[j], p);                \
      _Pragma("unroll")                                                        \
      for (int j = 0; j < 5; ++j) p = fmaf(wh[q][j], hh[j], p);                \
      pre[q] = p;                                                              \
    }                                                                          \
    float i_ = SIG(pre[0]), f_ = SIG(pre[1]);                                  \
    float g_ = TH(pre[2]),  o_ = SIG(pre[3]);                                  \
    float cn = fmaf(f_, c, i_ * g_);                                           \
    float hl = o_ * TH(cn);                                                    \
    float fv = fb;                                                             \
    _Pragma("unroll")                                                          \
    for (int j = 0; j < 5; ++j) fv = fmaf(wf[j], in[j], fv);                   \
    float fs = SIG(fv);                                                        \
    float fx = is_relu ? fmaxf(fv, 0.0f) : fs;                                 \
    float hn = is_fc ? fx : hl;                                                \
    bool ok = (k_ >= stage);                                                   \
    c  = ok ? cn : c;                                                          \
    hv = ok ? hn : hv;                                                         \
    if (is_fc2) outb[half][(k_ - 5) & 63][u] = fs;                             \
  }

#define FLUSH(TBASE)                                                           \
  { _Pragma("unroll")                                                          \
    for (int i2 = 0; i2 < 10; ++i2) {                                          \
      int idx = i2 * 64 + lane;                                                \
      int e  = (idx >= 320) ? 1 : 0;                                           \
      int r  = idx - e * 320;                                                  \
      int tq = r / 5;                                                          \
      int j2 = r - tq * 5;                                                     \
      int tt = (TBASE) + tq;                                                   \
      float v = outb[e][tt & 63][j2];                                          \
      if (tt >= 0 && tt < T_STEPS)                                             \
        out[((size_t)(b0 + e) * T_STEPS + tt) * 5 + j2] = v;                   \
    } }

  float hv = 0.f, c = 0.f;

  STAGE_CHUNK(0, 0)
  WAIT_VM0();

  for (int ch = 0; ch < 16; ++ch) {
    if (ch < 15) STAGE_CHUNK(ch + 1, (ch + 1) & 1)
    const int kb = ch * 64;
#pragma unroll 4
    for (int kk = 0; kk < 64; ++kk) TICK(kb + kk)
    FLUSH(kb - 5)
    WAIT_VM0();
  }
  // drain: 5 more ticks (stage>0 still consuming); xq reads are stale/unused
  for (int kk = 0; kk < 5; ++kk) TICK(T_STEPS + kk)
  FLUSH(T_STEPS - 5)

#undef STAGE_CHUNK
#undef TICK
#undef FLUSH
}

// ---------------------------------------------------------------------------
extern "C" void kernel_launch(void* const* d_in, const int* in_sizes, int n_in,
                              void* d_out, int out_size, void* d_ws, size_t ws_size,
                              hipStream_t stream)
{
  const float* x        = (const float*)d_in[0];
  const float* l1_Wih0  = (const float*)d_in[1];
  const float* l1_Whh0  = (const float*)d_in[2];
  const float* l1_bih0  = (const float*)d_in[3];
  const float* l1_bhh0  = (const float*)d_in[4];
  const float* l1_Wih1  = (const float*)d_in[5];
  const float* l1_Whh1  = (const float*)d_in[6];
  const float* l1_bih1  = (const float*)d_in[7];
  const float* l1_bhh1  = (const float*)d_in[8];
  const float* fc1_W    = (const float*)d_in[9];
  const float* fc1_b    = (const float*)d_in[10];
  const float* l2_Wih0  = (const float*)d_in[11];
  const float* l2_Whh0  = (const float*)d_in[12];
  const float* l2_bih0  = (const float*)d_in[13];
  const float* l2_bhh0  = (const float*)d_in[14];
  const float* l2_Wih1  = (const float*)d_in[15];
  const float* l2_Whh1  = (const float*)d_in[16];
  const float* l2_bih1  = (const float*)d_in[17];
  const float* l2_bhh1  = (const float*)d_in[18];
  const float* fc2_W    = (const float*)d_in[19];
  const float* fc2_b    = (const float*)d_in[20];

  float* xg   = (float*)d_ws;                  // 10,485,760 floats
  float* wtws = xg + 10485760;                 // 4,608 floats (W_T + bias)
  float* out  = (float*)d_out;

  prep_wt<<<dim3(18), dim3(256), 0, stream>>>(l1_Wih0, l1_bih0, l1_bhh0, wtws);

  xg_gemm<<<dim3(256), dim3(256), 0, stream>>>(x, wtws, xg);

  lstm_fused<<<dim3(B_SIZE / 2), dim3(64), 0, stream>>>(
      xg, out, l1_Whh0, l1_Wih1, l1_Whh1, l1_bih1, l1_bhh1,
      fc1_W, fc1_b, l2_Wih0, l2_Whh0, l2_bih0, l2_bhh0,
      l2_Wih1, l2_Whh1, l2_bih1, l2_bhh1, fc2_W, fc2_b);
}

// Round 6
// 422.724 us; speedup vs baseline: 1.5345x; 1.5345x over previous
//
#include <hip/hip_runtime.h>
#include <math.h>

#define T_STEPS 1024
#define B_SIZE  512
#define D_IN    225
#define WT_K    228
#define LOG2E   1.4426950408889634f

__device__ __forceinline__ float fexp2(float x) {
#if __has_builtin(__builtin_amdgcn_exp2f)
  return __builtin_amdgcn_exp2f(x);
#else
  return exp2f(x);
#endif
}
__device__ __forceinline__ float frcp(float x) {
#if __has_builtin(__builtin_amdgcn_rcpf)
  return __builtin_amdgcn_rcpf(x);
#else
  return 1.0f / x;
#endif
}
#define SIG(x) frcp(1.0f + fexp2((x) * (-LOG2E)))
#define TH(x)  fmaf(2.0f, frcp(1.0f + fexp2((x) * (-2.0f * LOG2E))), -1.0f)

#define GL16(gp, lp) __builtin_amdgcn_global_load_lds(                          \
    (const __attribute__((address_space(1))) void*)(gp),                        \
    (__attribute__((address_space(3))) void*)(lp), 16, 0, 0)
#define GL4(gp, lp)  __builtin_amdgcn_global_load_lds(                          \
    (const __attribute__((address_space(1))) void*)(gp),                        \
    (__attribute__((address_space(3))) void*)(lp), 4, 0, 0)

#define WAIT_VM0() do {                                                         \
    asm volatile("s_waitcnt vmcnt(0)" ::: "memory");                            \
    __builtin_amdgcn_sched_barrier(0);                                          \
  } while (0)
#define WAIT_VM10() do {                                                        \
    asm volatile("s_waitcnt vmcnt(10)" ::: "memory");                           \
    __builtin_amdgcn_sched_barrier(0);                                          \
  } while (0)

// -------- Kernel 0: wt2[g*228+k] = Wih[g*225+k] (pad 0); bias at 4560 -------
__global__ __launch_bounds__(256)
void prep_wt(const float* __restrict__ Wih, const float* __restrict__ bih,
             const float* __restrict__ bhh, float* __restrict__ wt2)
{
  int i = blockIdx.x * 256 + threadIdx.x;      // 0..4607
  int g = i / WT_K, kk = i - g * WT_K;
  float v = 0.f;
  if (g < 20 && kk < 225) v = Wih[g * 225 + kk];
  if (i >= 4560 && i < 4580) v = bih[i - 4560] + bhh[i - 4560];
  wt2[i] = v;
}

// -------- Kernel 1: xg' (permuted) = x @ Wih0^T + b  (round-4 structure) ----
// 8192 blocks x 256 thr; one 64-row tile per block staged via global_load_lds;
// 2 blocks/CU so staging hides under the co-resident block's compute.
// Output layout: xg'[row*20 + 4*u + q] (unit-major float4 for the LSTM kernel).
__global__ __launch_bounds__(256)
void xg_gemm(const float* __restrict__ x, const float* __restrict__ wtg,
             float* __restrict__ xg)
{
  __shared__ __align__(16) float xs[64 * D_IN];   // 57600 B
  __shared__ __align__(16) float wt[4608];        // 18432 B (tot 76032 -> 2/CU)
  const int tid  = threadIdx.x;
  const int lane = tid & 63;
  const int w    = __builtin_amdgcn_readfirstlane(tid >> 6);   // 0..3

  {   // stage W_T + bias: 18 x 256-dword chunks (waves 0,1: 5 ea; 2,3: 4 ea)
    int n0 = (w < 2) ? 5 : 4;
    int c0 = (w < 2) ? w * 5 : 10 + (w - 2) * 4;
    for (int m = 0; m < n0; ++m)
      GL16(wtg + (c0 + m) * 256 + lane * 4, wt + (c0 + m) * 256);
  }
  {   // stage x tile: 14400 dwords = 56 x 256 + 64
    const float* src = x + (size_t)blockIdx.x * (64 * D_IN);
    for (int m = 0; m < 14; ++m)
      GL16(src + (w * 14 + m) * 256 + lane * 4, xs + (w * 14 + m) * 256);
    if (w == 0) GL4(src + 14336 + lane, xs + 14336);
  }
  __syncthreads();

  const int row = lane;
  const float* xr = xs + row * D_IN;              // bank (row+k)%32: conflict-free
  const float* wr = wt + (5 * w) * WT_K;          // wave-uniform -> broadcast reads
  float acc[5];
#pragma unroll
  for (int j = 0; j < 5; ++j) acc[j] = wt[4560 + 5 * w + j];

#pragma unroll 8
  for (int kb = 0; kb < 224; kb += 4) {
    float x0 = xr[kb], x1 = xr[kb + 1], x2 = xr[kb + 2], x3 = xr[kb + 3];
#pragma unroll
    for (int j = 0; j < 5; ++j) {
      const float4 wv = *(const float4*)(wr + j * WT_K + kb);
      acc[j] = fmaf(x0, wv.x, acc[j]);
      acc[j] = fmaf(x1, wv.y, acc[j]);
      acc[j] = fmaf(x2, wv.z, acc[j]);
      acc[j] = fmaf(x3, wv.w, acc[j]);
    }
  }
  {
    float xl = xr[224];
#pragma unroll
    for (int j = 0; j < 5; ++j) acc[j] = fmaf(xl, wr[j * WT_K + 224], acc[j]);
  }
  // permuted store: gate (5w+j) -> slot 4*j + w
  float* op = xg + ((size_t)blockIdx.x * 64 + row) * 20 + w;
#pragma unroll
  for (int j = 0; j < 5; ++j) op[4 * j] = acc[j];
}

// -------- Kernel 2: 6-stage pipeline in one half-wave; lean ticks -----------
// Lanes (per 32-lane half): stage = l32/5 (L0,L1,FC1,L2,L3,FC2), u = l32%5;
// lanes 30,31 idle. h-exchange: 1 ds_write + 4 ds_read per tick into a tiny
// staged table (in-order DS pipe within one wave -> no barrier needed).
// FC stages folded into the gate-0 datapath (pre[0] with wh=0; sig==i_).
__global__ __launch_bounds__(64)
void lstm_fused(const float* __restrict__ xg, float* __restrict__ out,
              const float* __restrict__ l1_Whh0,
              const float* __restrict__ l1_Wih1, const float* __restrict__ l1_Whh1,
              const float* __restrict__ l1_bih1, const float* __restrict__ l1_bhh1,
              const float* __restrict__ fc1_W,  const float* __restrict__ fc1_b,
              const float* __restrict__ l2_Wih0, const float* __restrict__ l2_Whh0,
              const float* __restrict__ l2_bih0, const float* __restrict__ l2_bhh0,
              const float* __restrict__ l2_Wih1, const float* __restrict__ l2_Whh1,
              const float* __restrict__ l2_bih1, const float* __restrict__ l2_bhh1,
              const float* __restrict__ fc2_W,  const float* __restrict__ fc2_b)
{
  __shared__ __align__(16) float xq[2][2][1280];   // [buf][elem][64t*20] 20480 B
  __shared__ float outb[2][64][5];                 // 2560 B
  __shared__ __align__(16) float hx[128];          // [half][stage(8)][slot8] 512 B
  const int lane  = threadIdx.x & 63;
  const int half  = lane >> 5;
  const int l32   = lane & 31;
  const int stage = (l32 < 30) ? (l32 / 5) : 6;
  const int u     = (l32 < 30) ? (l32 - stage * 5) : 0;
  const int b0    = blockIdx.x * 2;

  const bool is_l0   = (stage == 0);
  const bool is_relu = (stage == 2);
  const bool is_fc   = (stage == 2) || (stage == 5);
  const bool is_fc2  = (stage == 5);

  float wi[4][5] = {}, wh[4][5] = {}, bs[4] = {};
  if (stage == 0) {
#pragma unroll
    for (int q = 0; q < 4; ++q)
#pragma unroll
      for (int j = 0; j < 5; ++j) wh[q][j] = l1_Whh0[(u + 5 * q) * 5 + j];
  } else if (stage == 1) {
#pragma unroll
    for (int q = 0; q < 4; ++q) {
#pragma unroll
      for (int j = 0; j < 5; ++j) {
        wi[q][j] = l1_Wih1[(u + 5 * q) * 5 + j];
        wh[q][j] = l1_Whh1[(u + 5 * q) * 5 + j];
      }
      bs[q] = l1_bih1[u + 5 * q] + l1_bhh1[u + 5 * q];
    }
  } else if (stage == 3) {
#pragma unroll
    for (int q = 0; q < 4; ++q) {
#pragma unroll
      for (int j = 0; j < 5; ++j) {
        wi[q][j] = l2_Wih0[(u + 5 * q) * 5 + j];
        wh[q][j] = l2_Whh0[(u + 5 * q) * 5 + j];
      }
      bs[q] = l2_bih0[u + 5 * q] + l2_bhh0[u + 5 * q];
    }
  } else if (stage == 4) {
#pragma unroll
    for (int q = 0; q < 4; ++q) {
#pragma unroll
      for (int j = 0; j < 5; ++j) {
        wi[q][j] = l2_Wih1[(u + 5 * q) * 5 + j];
        wh[q][j] = l2_Whh1[(u + 5 * q) * 5 + j];
      }
      bs[q] = l2_bih1[u + 5 * q] + l2_bhh1[u + 5 * q];
    }
  } else if (stage == 2) {      // FC1: pre[0] = fc1_W . in + fc1_b, wh = 0
#pragma unroll
    for (int j = 0; j < 5; ++j) wi[0][j] = fc1_W[u * 5 + j];
    bs[0] = fc1_b[u];
  } else if (stage == 5) {      // FC2: pre[0] = fc2_W . in + fc2_b
#pragma unroll
    for (int j = 0; j < 5; ++j) wi[0][j] = fc2_W[u * 5 + j];
    bs[0] = fc2_b[u];
  }

  float* hxp = hx;
  const int woff = half * 64 + stage * 8 + u;                 // own h slot
  const int ioff = half * 64 + ((stage > 0) ? stage - 1 : 0) * 8;  // prev-stage base
  const int hoff = half * 64 + stage * 8;                     // own-stage base

  for (int i = lane; i < 128; i += 64) hxp[i] = 0.f;

  const float* src0 = xg + (size_t)(b0 + 0) * T_STEPS * 20;
  const float* src1 = xg + (size_t)(b0 + 1) * T_STEPS * 20;

#define STAGE_CHUNK(CH, BUF)                                                   \
  { const float* s0_ = src0 + (CH) * 1280;                                     \
    const float* s1_ = src1 + (CH) * 1280;                                     \
    float* d0_ = &xq[BUF][0][0];                                               \
    float* d1_ = &xq[BUF][1][0];                                               \
    _Pragma("unroll")                                                          \
    for (int m = 0; m < 5; ++m) {                                              \
      GL16(s0_ + m * 256 + lane * 4, d0_ + m * 256);                           \
      GL16(s1_ + m * 256 + lane * 4, d1_ + m * 256);                           \
    } }

// One tick. GUARDED is a literal; KVAL only used when GUARDED.
#define TICKX(KK, XQB, GUARDED, KVAL)                                          \
  { hxp[woff] = hv;                          /* publish h(k-1)          */     \
    const float4 iv  = *(const float4*)(hxp + ioff);                           \
    const float  in4 = hxp[ioff + 4];                                          \
    const float4 hv4 = *(const float4*)(hxp + hoff);                           \
    const float  hh4 = hxp[hoff + 4];                                          \
    const float4 Qv  = *(const float4*)((XQB) + 20 * (KK));                    \
    const float inx[5] = {iv.x, iv.y, iv.z, iv.w, in4};                        \
    const float hhx[5] = {hv4.x, hv4.y, hv4.z, hv4.w, hh4};                    \
    float pre[4];                                                              \
    pre[0] = is_l0 ? Qv.x : bs[0];                                             \
    pre[1] = is_l0 ? Qv.y : bs[1];                                             \
    pre[2] = is_l0 ? Qv.z : bs[2];                                             \
    pre[3] = is_l0 ? Qv.w : bs[3];                                             \
    _Pragma("unroll")                                                          \
    for (int q = 0; q < 4; ++q) {                                              \
      _Pragma("unroll")                                                        \
      for (int j = 0; j < 5; ++j) pre[q] = fmaf(wi[q][j], inx[j], pre[q]);     \
      _Pragma("unroll")                                                        \
      for (int j = 0; j < 5; ++j) pre[q] = fmaf(wh[q][j], hhx[j], pre[q]);     \
    }                                                                          \
    float i_ = SIG(pre[0]), f_ = SIG(pre[1]);                                  \
    float g_ = TH(pre[2]),  o_ = SIG(pre[3]);                                  \
    float cn = fmaf(f_, c, i_ * g_);                                           \
    float hl = o_ * TH(cn);                                                    \
    float fx = is_relu ? fmaxf(pre[0], 0.0f) : i_;                             \
    float hn = is_fc ? fx : hl;                                                \
    if (GUARDED) { bool ok = (KVAL) >= stage; c = ok ? cn : c; hv = ok ? hn : hv; } \
    else         { c = cn; hv = hn; }                                          \
    if (is_fc2) outb[half][((KK) + 59) & 63][u] = i_;                          \
  }

#define FLUSH(TBASE)                                                           \
  { _Pragma("unroll")                                                          \
    for (int i2 = 0; i2 < 10; ++i2) {                                          \
      int idx = i2 * 64 + lane;                                                \
      int e  = (idx >= 320) ? 1 : 0;                                           \
      int r  = idx - e * 320;                                                  \
      int tq = r / 5;                                                          \
      int j2 = r - tq * 5;                                                     \
      int tt = (TBASE) + tq;                                                   \
      float v = outb[e][tt & 63][j2];                                          \
      if (tt >= 0 && tt < T_STEPS)                                             \
        out[((size_t)(b0 + e) * T_STEPS + tt) * 5 + j2] = v;                   \
    } }

  float hv = 0.f, c = 0.f;

  STAGE_CHUNK(0, 0)
  WAIT_VM0();

  { // chunk 0: 5 guarded ticks, then 59 lean ones
    STAGE_CHUNK(1, 1)
    const float* xqb = &xq[0][half][4 * u];
    for (int kk = 0; kk < 5; ++kk) TICKX(kk, xqb, true, kk)
#pragma unroll 4
    for (int kk = 5; kk < 64; ++kk) TICKX(kk, xqb, false, 0)
    FLUSH(-5)
    WAIT_VM10();
  }
  for (int ch = 1; ch < 16; ++ch) {
    if (ch < 15) STAGE_CHUNK(ch + 1, (ch + 1) & 1)
    const float* xqb = &xq[ch & 1][half][4 * u];
#pragma unroll 4
    for (int kk = 0; kk < 64; ++kk) TICKX(kk, xqb, false, 0)
    FLUSH(ch * 64 - 5)
    WAIT_VM10();
  }
  { // drain: 5 ticks (stale xq reads are unused downstream of t >= T)
    const float* xqb = &xq[0][half][4 * u];
    for (int kk = 0; kk < 5; ++kk) TICKX(kk, xqb, false, 0)
    FLUSH(T_STEPS - 5)
  }

#undef STAGE_CHUNK
#undef TICKX
#undef FLUSH
}

// ---------------------------------------------------------------------------
extern "C" void kernel_launch(void* const* d_in, const int* in_sizes, int n_in,
                              void* d_out, int out_size, void* d_ws, size_t ws_size,
                              hipStream_t stream)
{
  const float* x        = (const float*)d_in[0];
  const float* l1_Wih0  = (const float*)d_in[1];
  const float* l1_Whh0  = (const float*)d_in[2];
  const float* l1_bih0  = (const float*)d_in[3];
  const float* l1_bhh0  = (const float*)d_in[4];
  const float* l1_Wih1  = (const float*)d_in[5];
  const float* l1_Whh1  = (const float*)d_in[6];
  const float* l1_bih1  = (const float*)d_in[7];
  const float* l1_bhh1  = (const float*)d_in[8];
  const float* fc1_W    = (const float*)d_in[9];
  const float* fc1_b    = (const float*)d_in[10];
  const float* l2_Wih0  = (const float*)d_in[11];
  const float* l2_Whh0  = (const float*)d_in[12];
  const float* l2_bih0  = (const float*)d_in[13];
  const float* l2_bhh0  = (const float*)d_in[14];
  const float* l2_Wih1  = (const float*)d_in[15];
  const float* l2_Whh1  = (const float*)d_in[16];
  const float* l2_bih1  = (const float*)d_in[17];
  const float* l2_bhh1  = (const float*)d_in[18];
  const float* fc2_W    = (const float*)d_in[19];
  const float* fc2_b    = (const float*)d_in[20];

  float* xg   = (float*)d_ws;                  // 10,485,760 floats
  float* wtws = xg + 10485760;                 // 4,608 floats (W_T + bias)
  float* out  = (float*)d_out;

  prep_wt<<<dim3(18), dim3(256), 0, stream>>>(l1_Wih0, l1_bih0, l1_bhh0, wtws);

  xg_gemm<<<dim3((B_SIZE * T_STEPS) / 64), dim3(256), 0, stream>>>(x, wtws, xg);

  lstm_fused<<<dim3(B_SIZE / 2), dim3(64), 0, stream>>>(
      xg, out, l1_Whh0, l1_Wih1, l1_Whh1, l1_bih1, l1_bhh1,
      fc1_W, fc1_b, l2_Wih0, l2_Whh0, l2_bih0, l2_bhh0,
      l2_Wih1, l2_Whh1, l2_bih1, l2_bhh1, fc2_W, fc2_b);
}